// Round 9
// baseline (1561.452 us; speedup 1.0000x reference)
//
#include <hip/hip_runtime.h>
#include <cmath>
#include <cstdint>

typedef __bf16 bf16_t;
typedef __bf16 bf16x8 __attribute__((ext_vector_type(8)));
typedef __bf16 bf16x4 __attribute__((ext_vector_type(4)));
typedef float  f32x4  __attribute__((ext_vector_type(4)));

#define DEPTH 6
#define DIM   768
#define HEADS 12
#define DH    64
#define MLPD  3072
#define SEQ   1024
#define BATCH 4
#define MTOT  (BATCH*SEQ)   /* 4096 rows */
#define QKVN  2304          /* 3*768 */

static __device__ __forceinline__ bf16x8 ld8(const bf16_t* p) {
    return *(const bf16x8*)p;
}

// async global->LDS, 16B per lane. LDS dest is wave-uniform base + lane*16.
// We permute *source* addresses per lane to build XOR-swizzled LDS layouts.
typedef const __attribute__((address_space(1))) unsigned int gas_u32;
typedef __attribute__((address_space(3))) unsigned int las_u32;
static __device__ __forceinline__ void gload16(const bf16_t* g, bf16_t* l) {
    __builtin_amdgcn_global_load_lds((gas_u32*)g, (las_u32*)l, 16, 0, 0);
}

// ---------------- fp32 [K][N] -> bf16 [N][K] transposed weight ----------------
__global__ __launch_bounds__(256) void tcvt_kernel(const float* __restrict__ in,
                                                   bf16_t* __restrict__ out,
                                                   int K, int N) {
    __shared__ float ts[32][33];
    int n0 = blockIdx.x * 32, k0 = blockIdx.y * 32;
    size_t base = (size_t)blockIdx.z * K * N;
    int tx = threadIdx.x & 31, ty = threadIdx.x >> 5;   // 32 x 8
    #pragma unroll
    for (int r = 0; r < 32; r += 8)
        ts[ty + r][tx] = in[base + (size_t)(k0 + ty + r) * N + n0 + tx];
    __syncthreads();
    #pragma unroll
    for (int r = 0; r < 32; r += 8)
        out[base + (size_t)(n0 + ty + r) * K + k0 + tx] = (bf16_t)ts[tx][ty + r];
}

// ------- LN (+ optional bias add/writeback), one row per WAVE ----------------
// r9 rewrite: 256 thr = 4 waves = 4 rows; shuffle-xor butterfly reduction,
// zero LDS, zero barriers. Atomic split-K epilogues (see gemm_body EPI 2)
// already accumulated partials into x, so no P-slice pass exists anymore.
__global__ __launch_bounds__(256) void lnr_kernel(float* __restrict__ x,
                                                  const float* __restrict__ bias,
                                                  const float* __restrict__ w,
                                                  const float* __restrict__ b,
                                                  bf16_t* __restrict__ h,
                                                  int writeLN) {
    int lane = threadIdx.x & 63;
    int row = blockIdx.x * 4 + (threadIdx.x >> 6);
    float4* xr = (float4*)(x + (size_t)row * DIM);
    float4 v0 = xr[lane], v1 = xr[lane + 64], v2 = xr[lane + 128];
    if (bias) {
        const float4* bi = (const float4*)bias;
        float4 c0 = bi[lane], c1 = bi[lane + 64], c2 = bi[lane + 128];
        v0.x += c0.x; v0.y += c0.y; v0.z += c0.z; v0.w += c0.w;
        v1.x += c1.x; v1.y += c1.y; v1.z += c1.z; v1.w += c1.w;
        v2.x += c2.x; v2.y += c2.y; v2.z += c2.z; v2.w += c2.w;
        xr[lane] = v0; xr[lane + 64] = v1; xr[lane + 128] = v2;
    }
    float s = v0.x + v0.y + v0.z + v0.w + v1.x + v1.y + v1.z + v1.w
            + v2.x + v2.y + v2.z + v2.w;
    float q = v0.x * v0.x + v0.y * v0.y + v0.z * v0.z + v0.w * v0.w
            + v1.x * v1.x + v1.y * v1.y + v1.z * v1.z + v1.w * v1.w
            + v2.x * v2.x + v2.y * v2.y + v2.z * v2.z + v2.w * v2.w;
    #pragma unroll
    for (int off = 32; off > 0; off >>= 1) {
        s += __shfl_xor(s, off);
        q += __shfl_xor(q, off);
    }
    float mean = s * (1.0f / DIM);
    float rstd = rsqrtf(q * (1.0f / DIM) - mean * mean + 1e-5f);
    if (writeLN) {
        const float4* w4 = (const float4*)w;
        const float4* b4 = (const float4*)b;
        bf16_t* hr = h + (size_t)row * DIM;
        float4 vv[3] = {v0, v1, v2};
        #pragma unroll
        for (int k = 0; k < 3; k++) {
            float4 wv = w4[lane + 64 * k], bv = b4[lane + 64 * k];
            bf16x4 o;
            o[0] = (bf16_t)((vv[k].x - mean) * rstd * wv.x + bv.x);
            o[1] = (bf16_t)((vv[k].y - mean) * rstd * wv.y + bv.y);
            o[2] = (bf16_t)((vv[k].z - mean) * rstd * wv.z + bv.z);
            o[3] = (bf16_t)((vv[k].w - mean) * rstd * wv.w + bv.w);
            *(bf16x4*)&hr[(lane + 64 * k) * 4] = o;
        }
    }
}

// ---------------- bf16 MFMA GEMM body: 8-wave 256x64 tile (r8 structure) -----
// A: [M][K] bf16, Bt: [N][K] bf16. BM=256, BN=64, BK=32, 2-buf LDS (40KB).
// 512 threads / 8 waves (4m x 2n, each wave 64x32 out). Per iter:
// __syncthreads (drains own DMA) -> stage(it+1) async -> ds_read + 8 MFMA/wave.
// LDS layout: row-major [rows][32], chunk pos = chunk ^ ((row>>1)&3).
// XCD swizzle retained (null in r7 A/B but in best build, zero cost).
// EPI 0: Cb = A@B; V-tiles (n0>=1536) store transposed into Vt  (QKV)
// EPI 1: Cb = gelu(A@B+bias)                                    (MLP1)
// EPI 2: atomicAdd(Co, A@B) -- split-K accumulates straight into the fp32
//        residual stream; no partial buffers, no lnr P-pass.   (proj/MLP2)
template <int EPI>
static __device__ __forceinline__ void gemm_body(const bf16_t* __restrict__ A,
                                                 const bf16_t* __restrict__ Bt,
                                                 const float* __restrict__ bias,
                                                 bf16_t* __restrict__ Cb,
                                                 float* __restrict__ Co,
                                                 bf16_t* __restrict__ Vt,
                                                 int N, int K, int klen) {
    __shared__ __align__(16) bf16_t As[2][256 * 32];
    __shared__ __align__(16) bf16_t Bs[2][64 * 32];
    int t = threadIdx.x;
    // XCD-locality remap (bijective: gridDim.y=16, 16%8==0)
    int NX = gridDim.x;
    int flat = blockIdx.y * NX + blockIdx.x;
    int jj = flat >> 3;
    int bxs = jj % NX;
    int bys = (flat & 7) + ((jj / NX) << 3);
    int m0 = bys * 256, n0 = bxs * 64;
    int kz = blockIdx.z;
    int kbeg = kz * klen;
    int lane = t & 63, l16 = lane & 15, quad = lane >> 4;
    int wv = t >> 6;                    // 0..7
    int wm = wv >> 1, wn = wv & 1;      // 4 x 2 wave grid; wave = 64x32 out
    f32x4 acc[4][2] = {};

    // staging: wave wv stages A rows wv*32..wv*32+31 (two 1KB instrs);
    // waves 0..3 stage B rows wv*16..wv*16+15 (one instr).
    int sr = lane >> 2;
    int sc = ((lane & 3) ^ ((lane >> 3) & 3)) * 8;
    const bf16_t* gA0 = A  + (size_t)(m0 + wv * 32 + sr) * K + sc;
    const bf16_t* gA1 = gA0 + (size_t)16 * K;
    const bf16_t* gB0 = Bt + (size_t)(n0 + (wv & 3) * 16 + sr) * K + sc;
    bf16_t* lA0 = &As[0][(wv * 32) * 32];
    bf16_t* lA1 = &As[0][(wv * 32 + 16) * 32];
    bf16_t* lB0 = &Bs[0][((wv & 3) * 16) * 32];
    constexpr int bufA = 256 * 32;
    constexpr int bufB = 64 * 32;

    auto stage = [&](int buf, int k0) {
        gload16(gA0 + k0, lA0 + buf * bufA);
        gload16(gA1 + k0, lA1 + buf * bufA);
        if (wv < 4) gload16(gB0 + k0, lB0 + buf * bufB);
    };

    int nIt = klen >> 5;
    stage(0, kbeg);
    int posA = (quad ^ ((l16 >> 1) & 3)) * 8;   // swizzled frag chunk (2-way)

    for (int it = 0; it < nIt; it++) {
        __syncthreads();   // drains own DMA -> buf[it&1] ready; other buf free
        if (it + 1 < nIt) stage((it + 1) & 1, kbeg + (it + 1) * 32);
        const bf16_t* as = As[it & 1];
        const bf16_t* bs = Bs[it & 1];
        bf16x8 af[4], bfr[2];
        #pragma unroll
        for (int i = 0; i < 4; i++)
            af[i] = ld8(&as[(wm * 64 + i * 16 + l16) * 32 + posA]);
        #pragma unroll
        for (int j = 0; j < 2; j++)
            bfr[j] = ld8(&bs[(wn * 32 + j * 16 + l16) * 32 + posA]);
        #pragma unroll
        for (int i = 0; i < 4; i++)
            #pragma unroll
            for (int j = 0; j < 2; j++)
                acc[i][j] = __builtin_amdgcn_mfma_f32_16x16x32_bf16(af[i], bfr[j], acc[i][j], 0, 0, 0);
    }

    if constexpr (EPI == 0) {
        if (n0 >= 1536) {
            // V tile: store transposed into Vt[b][h][d][n], 8B per store.
            int b = m0 >> 10;
            #pragma unroll
            for (int i = 0; i < 4; i++) {
                int n = (m0 & 1023) + wm * 64 + i * 16 + quad * 4;
                #pragma unroll
                for (int j = 0; j < 2; j++) {
                    int hc = n0 + wn * 32 + j * 16 + l16 - 1536;
                    int hh = hc >> 6, d = hc & 63;
                    bf16x4 ov;
                    #pragma unroll
                    for (int r = 0; r < 4; r++) ov[r] = (bf16_t)acc[i][j][r];
                    *(bf16x4*)&Vt[(((size_t)b * HEADS + hh) * 64 + d) * SEQ + n] = ov;
                }
            }
            return;
        }
    }
    #pragma unroll
    for (int i = 0; i < 4; i++) {
        int grow = m0 + wm * 64 + i * 16 + quad * 4;
        #pragma unroll
        for (int j = 0; j < 2; j++) {
            int gcol = n0 + wn * 32 + j * 16 + l16;
            float bv = 0.0f;
            if constexpr (EPI == 1) bv = bias[gcol];
            #pragma unroll
            for (int r = 0; r < 4; r++) {
                size_t idx = (size_t)(grow + r) * N + gcol;
                float v = acc[i][j][r];
                if constexpr (EPI == 0) {
                    Cb[idx] = (bf16_t)v;
                } else if constexpr (EPI == 1) {
                    v += bv;
                    v = 0.5f * v * (1.0f + erff(v * 0.70710678118654752f));
                    Cb[idx] = (bf16_t)v;
                } else {
                    atomicAdd(&Co[idx], v);   // accumulate into residual stream
                }
            }
        }
    }
}

// Named wrappers: per-shape rocprof attribution.
__global__ __launch_bounds__(512) void qkv_gemm(const bf16_t* __restrict__ A,
                                                const bf16_t* __restrict__ Bt,
                                                bf16_t* __restrict__ Cb,
                                                bf16_t* __restrict__ Vt) {
    gemm_body<0>(A, Bt, nullptr, Cb, nullptr, Vt, QKVN, DIM, DIM);
}
__global__ __launch_bounds__(512) void proj_gemm(const bf16_t* __restrict__ A,
                                                 const bf16_t* __restrict__ Bt,
                                                 float* __restrict__ Co) {
    gemm_body<2>(A, Bt, nullptr, nullptr, Co, nullptr, DIM, DIM, 192);
}
__global__ __launch_bounds__(512) void mlp1_gemm(const bf16_t* __restrict__ A,
                                                 const bf16_t* __restrict__ Bt,
                                                 const float* __restrict__ bias,
                                                 bf16_t* __restrict__ Cb) {
    gemm_body<1>(A, Bt, bias, Cb, nullptr, nullptr, MLPD, DIM, DIM);
}
__global__ __launch_bounds__(512) void mlp2_gemm(const bf16_t* __restrict__ A,
                                                 const bf16_t* __restrict__ Bt,
                                                 float* __restrict__ Co) {
    gemm_body<2>(A, Bt, nullptr, nullptr, Co, nullptr, DIM, MLPD, 768);
}

// ---------------- flash attention v4 (r8, unchanged) ------------------------
__global__ __launch_bounds__(256) void attn_kernel(const bf16_t* __restrict__ qkv,
                                                   const bf16_t* __restrict__ vt,
                                                   bf16_t* __restrict__ out) {
    int flat = (blockIdx.z * gridDim.y + blockIdx.y) * gridDim.x + blockIdx.x;
    int jj = flat >> 3;
    int qt = jj & 15;                       // gridDim.x == 16
    int bh = (flat & 7) + ((jj >> 4) << 3); // in [0, 48)
    int h = bh % HEADS, b = bh / HEADS;
    int t = threadIdx.x;
    int wv = t >> 6, lane = t & 63, l16 = lane & 15, quad = lane >> 4;
    const float LOG2E = 1.44269504f;
    int qw0 = qt * 64 + wv * 16;

    __shared__ __align__(16) bf16_t Ks[2][64 * 64];
    __shared__ __align__(16) bf16_t Vs[2][64 * 64];
    __shared__ __align__(16) bf16_t Pa[4][16 * 72];
    bf16_t* P = Pa[wv];

    size_t bS = (size_t)b * SEQ;
    const bf16_t* qrow = qkv + (bS + qw0 + l16) * QKVN + h * 64;
    bf16x8 qf0 = ld8(qrow + quad * 8);
    bf16x8 qf1 = ld8(qrow + 32 + quad * 8);

    float m = -3e38f, l = 0.0f;
    f32x4 o[4] = {};

    const bf16_t* kbase = qkv + bS * QKVN + 768 + h * 64;
    const bf16_t* vbase = vt + ((size_t)(b * HEADS + h) * 64) * SEQ;

    int ar = lane >> 3;
    int ac = ((lane & 7) ^ ar) * 8;
    int i0 = wv * 2, i1 = wv * 2 + 1;
    const bf16_t* gK0 = kbase + (size_t)(i0 * 8 + ar) * QKVN + ac;
    const bf16_t* gK1 = kbase + (size_t)(i1 * 8 + ar) * QKVN + ac;
    const bf16_t* gV0 = vbase + (size_t)(i0 * 8 + ar) * SEQ + ac;
    const bf16_t* gV1 = vbase + (size_t)(i1 * 8 + ar) * SEQ + ac;

    auto stage = [&](int buf, int kb) {
        gload16(gK0 + (size_t)kb * QKVN, &Ks[buf][i0 * 8 * 64]);
        gload16(gK1 + (size_t)kb * QKVN, &Ks[buf][i1 * 8 * 64]);
        gload16(gV0 + kb, &Vs[buf][i0 * 8 * 64]);
        gload16(gV1 + kb, &Vs[buf][i1 * 8 * 64]);
    };

    stage(0, 0);
    int p0 = (quad ^ (l16 & 7)) * 8;         // chunks 0..3 (swizzled)
    int p1 = ((quad + 4) ^ (l16 & 7)) * 8;   // chunks 4..7 (swizzled)

    for (int it = 0; it < SEQ / 64; it++) {
        __syncthreads();
        if (it + 1 < SEQ / 64) stage((it + 1) & 1, (it + 1) * 64);
        const bf16_t* ks = Ks[it & 1];
        const bf16_t* vs = Vs[it & 1];

        f32x4 s[4];
        #pragma unroll
        for (int tt = 0; tt < 4; tt++) {
            const bf16_t* kr = &ks[(tt * 16 + l16) * 64];
            f32x4 z = {};
            z = __builtin_amdgcn_mfma_f32_16x16x32_bf16(ld8(kr + p0), qf0, z, 0, 0, 0);
            z = __builtin_amdgcn_mfma_f32_16x16x32_bf16(ld8(kr + p1), qf1, z, 0, 0, 0);
            s[tt] = z;
        }
        float mx = -3e38f;
        #pragma unroll
        for (int tt = 0; tt < 4; tt++)
            #pragma unroll
            for (int r = 0; r < 4; r++) {
                s[tt][r] *= 0.125f;
                mx = fmaxf(mx, s[tt][r]);
            }
        mx = fmaxf(mx, __shfl_xor(mx, 16));
        mx = fmaxf(mx, __shfl_xor(mx, 32));
        float mn = fmaxf(m, mx);
        float alpha = exp2f((m - mn) * LOG2E);
        m = mn;
        float nb = mn * LOG2E;
        float rs = 0.0f;
        #pragma unroll
        for (int tt = 0; tt < 4; tt++) {
            bf16x4 pkt;
            #pragma unroll
            for (int r = 0; r < 4; r++) {
                float p = exp2f(fmaf(s[tt][r], LOG2E, -nb));
                rs += p;
                pkt[r] = (bf16_t)p;
            }
            *(bf16x4*)&P[l16 * 72 + tt * 16 + quad * 4] = pkt;
        }
        l = l * alpha + rs;   // quad-partial; reduced at end
        #pragma unroll
        for (int jt = 0; jt < 4; jt++) o[jt] *= alpha;
        asm volatile("s_waitcnt lgkmcnt(0)" ::: "memory");  // per-wave P visible
        bf16x8 pf0 = ld8(&P[l16 * 72 + quad * 8]);
        bf16x8 pf1 = ld8(&P[l16 * 72 + 32 + quad * 8]);
        #pragma unroll
        for (int jt = 0; jt < 4; jt++) {
            const bf16_t* vr = &vs[(jt * 16 + l16) * 64];
            o[jt] = __builtin_amdgcn_mfma_f32_16x16x32_bf16(ld8(vr + p0), pf0, o[jt], 0, 0, 0);
            o[jt] = __builtin_amdgcn_mfma_f32_16x16x32_bf16(ld8(vr + p1), pf1, o[jt], 0, 0, 0);
        }
    }

    l += __shfl_xor(l, 16);
    l += __shfl_xor(l, 32);
    float inv = 1.0f / l;
    bf16_t* orow = out + (bS + qw0 + l16) * DIM + h * 64;
    #pragma unroll
    for (int jt = 0; jt < 4; jt++) {
        bf16x4 ov;
        #pragma unroll
        for (int r = 0; r < 4; r++) ov[r] = (bf16_t)(o[jt][r] * inv);
        *(bf16x4*)&orow[jt * 16 + quad * 4] = ov;
    }
}

extern "C" void kernel_launch(void* const* d_in, const int* in_sizes, int n_in,
                              void* d_out, int out_size, void* d_ws, size_t ws_size,
                              hipStream_t stream) {
    const float* x     = (const float*)d_in[0];
    const float* ln1_w = (const float*)d_in[1];
    const float* ln1_b = (const float*)d_in[2];
    const float* w_qkv = (const float*)d_in[3];
    const float* w_o   = (const float*)d_in[4];
    const float* b_o   = (const float*)d_in[5];
    const float* ln2_w = (const float*)d_in[6];
    const float* ln2_b = (const float*)d_in[7];
    const float* w1    = (const float*)d_in[8];
    const float* b1    = (const float*)d_in[9];
    const float* w2    = (const float*)d_in[10];
    const float* b2    = (const float*)d_in[11];
    float* out = (float*)d_out;

    char* ws = (char*)d_ws;
    size_t off = 0;
    auto alloc = [&](size_t bytes) -> char* {
        char* p = ws + off;
        off += (bytes + 255) & ~(size_t)255;
        return p;
    };
    bf16_t* wqkv_t = (bf16_t*)alloc((size_t)DEPTH * DIM * QKVN * 2);
    bf16_t* wo_t   = (bf16_t*)alloc((size_t)DEPTH * DIM * DIM * 2);
    bf16_t* w1_t   = (bf16_t*)alloc((size_t)DEPTH * DIM * MLPD * 2);
    bf16_t* w2_t   = (bf16_t*)alloc((size_t)DEPTH * MLPD * DIM * 2);
    bf16_t* hbuf   = (bf16_t*)alloc((size_t)MTOT * DIM * 2);
    bf16_t* qkvb   = (bf16_t*)alloc((size_t)MTOT * QKVN * 2);
    bf16_t* vtb    = (bf16_t*)alloc((size_t)BATCH * HEADS * 64 * SEQ * 2);
    bf16_t* aob    = (bf16_t*)alloc((size_t)MTOT * DIM * 2);
    bf16_t* midb   = (bf16_t*)alloc((size_t)MTOT * MLPD * 2);
    if (off > ws_size) return;

    tcvt_kernel<<<dim3(QKVN / 32, DIM / 32, DEPTH), 256, 0, stream>>>(w_qkv, wqkv_t, DIM, QKVN);
    tcvt_kernel<<<dim3(DIM / 32,  DIM / 32, DEPTH), 256, 0, stream>>>(w_o,   wo_t,   DIM, DIM);
    tcvt_kernel<<<dim3(MLPD / 32, DIM / 32, DEPTH), 256, 0, stream>>>(w1,    w1_t,   DIM, MLPD);
    tcvt_kernel<<<dim3(DIM / 32, MLPD / 32, DEPTH), 256, 0, stream>>>(w2,    w2_t,   MLPD, DIM);

    hipMemcpyAsync(out, x, (size_t)MTOT * DIM * 4, hipMemcpyDeviceToDevice, stream);

    // initial LN1 (layer 0): pure LN of x
    lnr_kernel<<<MTOT / 4, 256, 0, stream>>>(out, nullptr, ln1_w, ln1_b, hbuf, 1);

    for (int L = 0; L < DEPTH; L++) {
        qkv_gemm<<<dim3(QKVN / 64, MTOT / 256, 1), 512, 0, stream>>>(
            hbuf, wqkv_t + (size_t)L * DIM * QKVN, qkvb, vtb);
        attn_kernel<<<dim3(SEQ / 64, HEADS, BATCH), 256, 0, stream>>>(qkvb, vtb, aob);
        // proj: split-4 (768 blocks, 3/CU), atomically accumulates into out
        proj_gemm<<<dim3(DIM / 64, MTOT / 256, 4), 512, 0, stream>>>(
            aob, wo_t + (size_t)L * DIM * DIM, out);
        lnr_kernel<<<MTOT / 4, 256, 0, stream>>>(out, b_o + L * DIM,
                                                 ln2_w + L * DIM, ln2_b + L * DIM,
                                                 hbuf, 1);
        mlp1_gemm<<<dim3(MLPD / 64, MTOT / 256, 1), 512, 0, stream>>>(
            hbuf, w1_t + (size_t)L * DIM * MLPD, b1 + L * MLPD, midb);
        // MLP2: split-4, atomically accumulates into out
        mlp2_gemm<<<dim3(DIM / 64, MTOT / 256, 4), 512, 0, stream>>>(
            midb, w2_t + (size_t)L * MLPD * DIM, out);
        if (L < DEPTH - 1) {
            lnr_kernel<<<MTOT / 4, 256, 0, stream>>>(out, b2 + L * DIM,
                                                     ln1_w + (L + 1) * DIM,
                                                     ln1_b + (L + 1) * DIM, hbuf, 1);
        } else {
            lnr_kernel<<<MTOT / 4, 256, 0, stream>>>(out, b2 + L * DIM,
                                                     nullptr, nullptr, nullptr, 0);
        }
    }
}

// Round 10
// 1290.945 us; speedup vs baseline: 1.2095x; 1.2095x over previous
//
#include <hip/hip_runtime.h>
#include <cmath>
#include <cstdint>

typedef __bf16 bf16_t;
typedef __bf16 bf16x8 __attribute__((ext_vector_type(8)));
typedef __bf16 bf16x4 __attribute__((ext_vector_type(4)));
typedef float  f32x4  __attribute__((ext_vector_type(4)));

#define DEPTH 6
#define DIM   768
#define HEADS 12
#define DH    64
#define MLPD  3072
#define SEQ   1024
#define BATCH 4
#define MTOT  (BATCH*SEQ)   /* 4096 rows */
#define QKVN  2304          /* 3*768 */

static __device__ __forceinline__ bf16x8 ld8(const bf16_t* p) {
    return *(const bf16x8*)p;
}

// async global->LDS, 16B per lane. LDS dest is wave-uniform base + lane*16.
// We permute *source* addresses per lane to build XOR-swizzled LDS layouts.
typedef const __attribute__((address_space(1))) unsigned int gas_u32;
typedef __attribute__((address_space(3))) unsigned int las_u32;
static __device__ __forceinline__ void gload16(const bf16_t* g, bf16_t* l) {
    __builtin_amdgcn_global_load_lds((gas_u32*)g, (las_u32*)l, 16, 0, 0);
}

// ---------------- fp32 [K][N] -> bf16 [N][K] transposed weight ----------------
__global__ __launch_bounds__(256) void tcvt_kernel(const float* __restrict__ in,
                                                   bf16_t* __restrict__ out,
                                                   int K, int N) {
    __shared__ float ts[32][33];
    int n0 = blockIdx.x * 32, k0 = blockIdx.y * 32;
    size_t base = (size_t)blockIdx.z * K * N;
    int tx = threadIdx.x & 31, ty = threadIdx.x >> 5;   // 32 x 8
    #pragma unroll
    for (int r = 0; r < 32; r += 8)
        ts[ty + r][tx] = in[base + (size_t)(k0 + ty + r) * N + n0 + tx];
    __syncthreads();
    #pragma unroll
    for (int r = 0; r < 32; r += 8)
        out[base + (size_t)(n0 + ty + r) * K + k0 + tx] = (bf16_t)ts[tx][ty + r];
}

// ------- fused: x += bias + sum(P slices); write x and LN(x) -----------------
// One row per WAVE (256 thr = 4 rows): shuffle-xor butterfly, no LDS/barriers.
// r10: r9's wave-per-row form + restored split-K P-slice reduction (the
// atomicAdd epilogue was falsified in r9: RMW traffic + serialization,
// WRITE unchanged 49MB, FETCH +9MB, mlp2 45->66us).
__global__ __launch_bounds__(256) void lnr_kernel(float* __restrict__ x,
                                                  const float* __restrict__ P,
                                                  int nslices,
                                                  const float* __restrict__ bias,
                                                  const float* __restrict__ w,
                                                  const float* __restrict__ b,
                                                  bf16_t* __restrict__ h,
                                                  int writeLN) {
    int lane = threadIdx.x & 63;
    int row = blockIdx.x * 4 + (threadIdx.x >> 6);
    float4* xr = (float4*)(x + (size_t)row * DIM);
    float4 v0 = xr[lane], v1 = xr[lane + 64], v2 = xr[lane + 128];
    if (nslices) {
        const float4* bi = (const float4*)bias;
        float4 c0 = bi[lane], c1 = bi[lane + 64], c2 = bi[lane + 128];
        v0.x += c0.x; v0.y += c0.y; v0.z += c0.z; v0.w += c0.w;
        v1.x += c1.x; v1.y += c1.y; v1.z += c1.z; v1.w += c1.w;
        v2.x += c2.x; v2.y += c2.y; v2.z += c2.z; v2.w += c2.w;
        for (int s = 0; s < nslices; s++) {
            const float4* pr = (const float4*)(P + (size_t)s * MTOT * DIM
                                                 + (size_t)row * DIM);
            float4 p0 = pr[lane], p1 = pr[lane + 64], p2 = pr[lane + 128];
            v0.x += p0.x; v0.y += p0.y; v0.z += p0.z; v0.w += p0.w;
            v1.x += p1.x; v1.y += p1.y; v1.z += p1.z; v1.w += p1.w;
            v2.x += p2.x; v2.y += p2.y; v2.z += p2.z; v2.w += p2.w;
        }
        xr[lane] = v0; xr[lane + 64] = v1; xr[lane + 128] = v2;
    }
    float s = v0.x + v0.y + v0.z + v0.w + v1.x + v1.y + v1.z + v1.w
            + v2.x + v2.y + v2.z + v2.w;
    float q = v0.x * v0.x + v0.y * v0.y + v0.z * v0.z + v0.w * v0.w
            + v1.x * v1.x + v1.y * v1.y + v1.z * v1.z + v1.w * v1.w
            + v2.x * v2.x + v2.y * v2.y + v2.z * v2.z + v2.w * v2.w;
    #pragma unroll
    for (int off = 32; off > 0; off >>= 1) {
        s += __shfl_xor(s, off);
        q += __shfl_xor(q, off);
    }
    float mean = s * (1.0f / DIM);
    float rstd = rsqrtf(q * (1.0f / DIM) - mean * mean + 1e-5f);
    if (writeLN) {
        const float4* w4 = (const float4*)w;
        const float4* b4 = (const float4*)b;
        bf16_t* hr = h + (size_t)row * DIM;
        float4 vv[3] = {v0, v1, v2};
        #pragma unroll
        for (int k = 0; k < 3; k++) {
            float4 wv = w4[lane + 64 * k], bv = b4[lane + 64 * k];
            bf16x4 o;
            o[0] = (bf16_t)((vv[k].x - mean) * rstd * wv.x + bv.x);
            o[1] = (bf16_t)((vv[k].y - mean) * rstd * wv.y + bv.y);
            o[2] = (bf16_t)((vv[k].z - mean) * rstd * wv.z + bv.z);
            o[3] = (bf16_t)((vv[k].w - mean) * rstd * wv.w + bv.w);
            *(bf16x4*)&hr[(lane + 64 * k) * 4] = o;
        }
    }
}

// ---------------- bf16 MFMA GEMM body: 8-wave 256x64 tile (r8 structure) -----
// A: [M][K] bf16, Bt: [N][K] bf16. BM=256, BN=64, BK=32, 2-buf LDS (40KB).
// 512 threads / 8 waves (4m x 2n, each wave 64x32 out). Per iter:
// __syncthreads (drains own DMA) -> stage(it+1) async -> ds_read + 8 MFMA/wave.
// LDS layout: row-major [rows][32], chunk pos = chunk ^ ((row>>1)&3).
// XCD swizzle retained (null in r7 A/B but zero cost).
// EPI 0: Cb = A@B; V-tiles (n0>=1536) store transposed into Vt  (QKV)
// EPI 1: Cb = gelu(A@B+bias)                                    (MLP1)
// EPI 2: Cf[slice] = A@B  (plain fp32 partial store, split-K)   (proj/MLP2)
template <int EPI>
static __device__ __forceinline__ void gemm_body(const bf16_t* __restrict__ A,
                                                 const bf16_t* __restrict__ Bt,
                                                 const float* __restrict__ bias,
                                                 bf16_t* __restrict__ Cb,
                                                 float* __restrict__ Cf,
                                                 bf16_t* __restrict__ Vt,
                                                 int N, int K, int klen) {
    __shared__ __align__(16) bf16_t As[2][256 * 32];
    __shared__ __align__(16) bf16_t Bs[2][64 * 32];
    int t = threadIdx.x;
    // XCD-locality remap (bijective: gridDim.y=16, 16%8==0)
    int NX = gridDim.x;
    int flat = blockIdx.y * NX + blockIdx.x;
    int jj = flat >> 3;
    int bxs = jj % NX;
    int bys = (flat & 7) + ((jj / NX) << 3);
    int m0 = bys * 256, n0 = bxs * 64;
    int kz = blockIdx.z;
    int kbeg = kz * klen;
    int lane = t & 63, l16 = lane & 15, quad = lane >> 4;
    int wv = t >> 6;                    // 0..7
    int wm = wv >> 1, wn = wv & 1;      // 4 x 2 wave grid; wave = 64x32 out
    f32x4 acc[4][2] = {};

    // staging: wave wv stages A rows wv*32..wv*32+31 (two 1KB instrs);
    // waves 0..3 stage B rows wv*16..wv*16+15 (one instr).
    int sr = lane >> 2;
    int sc = ((lane & 3) ^ ((lane >> 3) & 3)) * 8;
    const bf16_t* gA0 = A  + (size_t)(m0 + wv * 32 + sr) * K + sc;
    const bf16_t* gA1 = gA0 + (size_t)16 * K;
    const bf16_t* gB0 = Bt + (size_t)(n0 + (wv & 3) * 16 + sr) * K + sc;
    bf16_t* lA0 = &As[0][(wv * 32) * 32];
    bf16_t* lA1 = &As[0][(wv * 32 + 16) * 32];
    bf16_t* lB0 = &Bs[0][((wv & 3) * 16) * 32];
    constexpr int bufA = 256 * 32;
    constexpr int bufB = 64 * 32;

    auto stage = [&](int buf, int k0) {
        gload16(gA0 + k0, lA0 + buf * bufA);
        gload16(gA1 + k0, lA1 + buf * bufA);
        if (wv < 4) gload16(gB0 + k0, lB0 + buf * bufB);
    };

    int nIt = klen >> 5;
    stage(0, kbeg);
    int posA = (quad ^ ((l16 >> 1) & 3)) * 8;   // swizzled frag chunk (2-way)

    for (int it = 0; it < nIt; it++) {
        __syncthreads();   // drains own DMA -> buf[it&1] ready; other buf free
        if (it + 1 < nIt) stage((it + 1) & 1, kbeg + (it + 1) * 32);
        const bf16_t* as = As[it & 1];
        const bf16_t* bs = Bs[it & 1];
        bf16x8 af[4], bfr[2];
        #pragma unroll
        for (int i = 0; i < 4; i++)
            af[i] = ld8(&as[(wm * 64 + i * 16 + l16) * 32 + posA]);
        #pragma unroll
        for (int j = 0; j < 2; j++)
            bfr[j] = ld8(&bs[(wn * 32 + j * 16 + l16) * 32 + posA]);
        #pragma unroll
        for (int i = 0; i < 4; i++)
            #pragma unroll
            for (int j = 0; j < 2; j++)
                acc[i][j] = __builtin_amdgcn_mfma_f32_16x16x32_bf16(af[i], bfr[j], acc[i][j], 0, 0, 0);
    }

    if constexpr (EPI == 0) {
        if (n0 >= 1536) {
            // V tile: store transposed into Vt[b][h][d][n], 8B per store.
            int b = m0 >> 10;
            #pragma unroll
            for (int i = 0; i < 4; i++) {
                int n = (m0 & 1023) + wm * 64 + i * 16 + quad * 4;
                #pragma unroll
                for (int j = 0; j < 2; j++) {
                    int hc = n0 + wn * 32 + j * 16 + l16 - 1536;
                    int hh = hc >> 6, d = hc & 63;
                    bf16x4 ov;
                    #pragma unroll
                    for (int r = 0; r < 4; r++) ov[r] = (bf16_t)acc[i][j][r];
                    *(bf16x4*)&Vt[(((size_t)b * HEADS + hh) * 64 + d) * SEQ + n] = ov;
                }
            }
            return;
        }
    }
    #pragma unroll
    for (int i = 0; i < 4; i++) {
        int grow = m0 + wm * 64 + i * 16 + quad * 4;
        #pragma unroll
        for (int j = 0; j < 2; j++) {
            int gcol = n0 + wn * 32 + j * 16 + l16;
            float bv = 0.0f;
            if constexpr (EPI == 1) bv = bias[gcol];
            #pragma unroll
            for (int r = 0; r < 4; r++) {
                size_t idx = (size_t)(grow + r) * N + gcol;
                float v = acc[i][j][r];
                if constexpr (EPI == 0) {
                    Cb[idx] = (bf16_t)v;
                } else if constexpr (EPI == 1) {
                    v += bv;
                    v = 0.5f * v * (1.0f + erff(v * 0.70710678118654752f));
                    Cb[idx] = (bf16_t)v;
                } else {
                    Cf[(size_t)kz * MTOT * N + idx] = v;   // plain partial store
                }
            }
        }
    }
}

// Named wrappers: per-shape rocprof attribution.
__global__ __launch_bounds__(512) void qkv_gemm(const bf16_t* __restrict__ A,
                                                const bf16_t* __restrict__ Bt,
                                                bf16_t* __restrict__ Cb,
                                                bf16_t* __restrict__ Vt) {
    gemm_body<0>(A, Bt, nullptr, Cb, nullptr, Vt, QKVN, DIM, DIM);
}
__global__ __launch_bounds__(512) void proj_gemm(const bf16_t* __restrict__ A,
                                                 const bf16_t* __restrict__ Bt,
                                                 float* __restrict__ Cf) {
    gemm_body<2>(A, Bt, nullptr, nullptr, Cf, nullptr, DIM, DIM, 384);
}
__global__ __launch_bounds__(512) void mlp1_gemm(const bf16_t* __restrict__ A,
                                                 const bf16_t* __restrict__ Bt,
                                                 const float* __restrict__ bias,
                                                 bf16_t* __restrict__ Cb) {
    gemm_body<1>(A, Bt, bias, Cb, nullptr, nullptr, MLPD, DIM, DIM);
}
__global__ __launch_bounds__(512) void mlp2_gemm(const bf16_t* __restrict__ A,
                                                 const bf16_t* __restrict__ Bt,
                                                 float* __restrict__ Cf) {
    gemm_body<2>(A, Bt, nullptr, nullptr, Cf, nullptr, DIM, MLPD, 768);
}

// ---------------- flash attention v4 (r8, unchanged) ------------------------
__global__ __launch_bounds__(256) void attn_kernel(const bf16_t* __restrict__ qkv,
                                                   const bf16_t* __restrict__ vt,
                                                   bf16_t* __restrict__ out) {
    int flat = (blockIdx.z * gridDim.y + blockIdx.y) * gridDim.x + blockIdx.x;
    int jj = flat >> 3;
    int qt = jj & 15;                       // gridDim.x == 16
    int bh = (flat & 7) + ((jj >> 4) << 3); // in [0, 48)
    int h = bh % HEADS, b = bh / HEADS;
    int t = threadIdx.x;
    int wv = t >> 6, lane = t & 63, l16 = lane & 15, quad = lane >> 4;
    const float LOG2E = 1.44269504f;
    int qw0 = qt * 64 + wv * 16;

    __shared__ __align__(16) bf16_t Ks[2][64 * 64];
    __shared__ __align__(16) bf16_t Vs[2][64 * 64];
    __shared__ __align__(16) bf16_t Pa[4][16 * 72];
    bf16_t* P = Pa[wv];

    size_t bS = (size_t)b * SEQ;
    const bf16_t* qrow = qkv + (bS + qw0 + l16) * QKVN + h * 64;
    bf16x8 qf0 = ld8(qrow + quad * 8);
    bf16x8 qf1 = ld8(qrow + 32 + quad * 8);

    float m = -3e38f, l = 0.0f;
    f32x4 o[4] = {};

    const bf16_t* kbase = qkv + bS * QKVN + 768 + h * 64;
    const bf16_t* vbase = vt + ((size_t)(b * HEADS + h) * 64) * SEQ;

    int ar = lane >> 3;
    int ac = ((lane & 7) ^ ar) * 8;
    int i0 = wv * 2, i1 = wv * 2 + 1;
    const bf16_t* gK0 = kbase + (size_t)(i0 * 8 + ar) * QKVN + ac;
    const bf16_t* gK1 = kbase + (size_t)(i1 * 8 + ar) * QKVN + ac;
    const bf16_t* gV0 = vbase + (size_t)(i0 * 8 + ar) * SEQ + ac;
    const bf16_t* gV1 = vbase + (size_t)(i1 * 8 + ar) * SEQ + ac;

    auto stage = [&](int buf, int kb) {
        gload16(gK0 + (size_t)kb * QKVN, &Ks[buf][i0 * 8 * 64]);
        gload16(gK1 + (size_t)kb * QKVN, &Ks[buf][i1 * 8 * 64]);
        gload16(gV0 + kb, &Vs[buf][i0 * 8 * 64]);
        gload16(gV1 + kb, &Vs[buf][i1 * 8 * 64]);
    };

    stage(0, 0);
    int p0 = (quad ^ (l16 & 7)) * 8;         // chunks 0..3 (swizzled)
    int p1 = ((quad + 4) ^ (l16 & 7)) * 8;   // chunks 4..7 (swizzled)

    for (int it = 0; it < SEQ / 64; it++) {
        __syncthreads();
        if (it + 1 < SEQ / 64) stage((it + 1) & 1, (it + 1) * 64);
        const bf16_t* ks = Ks[it & 1];
        const bf16_t* vs = Vs[it & 1];

        f32x4 s[4];
        #pragma unroll
        for (int tt = 0; tt < 4; tt++) {
            const bf16_t* kr = &ks[(tt * 16 + l16) * 64];
            f32x4 z = {};
            z = __builtin_amdgcn_mfma_f32_16x16x32_bf16(ld8(kr + p0), qf0, z, 0, 0, 0);
            z = __builtin_amdgcn_mfma_f32_16x16x32_bf16(ld8(kr + p1), qf1, z, 0, 0, 0);
            s[tt] = z;
        }
        float mx = -3e38f;
        #pragma unroll
        for (int tt = 0; tt < 4; tt++)
            #pragma unroll
            for (int r = 0; r < 4; r++) {
                s[tt][r] *= 0.125f;
                mx = fmaxf(mx, s[tt][r]);
            }
        mx = fmaxf(mx, __shfl_xor(mx, 16));
        mx = fmaxf(mx, __shfl_xor(mx, 32));
        float mn = fmaxf(m, mx);
        float alpha = exp2f((m - mn) * LOG2E);
        m = mn;
        float nb = mn * LOG2E;
        float rs = 0.0f;
        #pragma unroll
        for (int tt = 0; tt < 4; tt++) {
            bf16x4 pkt;
            #pragma unroll
            for (int r = 0; r < 4; r++) {
                float p = exp2f(fmaf(s[tt][r], LOG2E, -nb));
                rs += p;
                pkt[r] = (bf16_t)p;
            }
            *(bf16x4*)&P[l16 * 72 + tt * 16 + quad * 4] = pkt;
        }
        l = l * alpha + rs;   // quad-partial; reduced at end
        #pragma unroll
        for (int jt = 0; jt < 4; jt++) o[jt] *= alpha;
        asm volatile("s_waitcnt lgkmcnt(0)" ::: "memory");  // per-wave P visible
        bf16x8 pf0 = ld8(&P[l16 * 72 + quad * 8]);
        bf16x8 pf1 = ld8(&P[l16 * 72 + 32 + quad * 8]);
        #pragma unroll
        for (int jt = 0; jt < 4; jt++) {
            const bf16_t* vr = &vs[(jt * 16 + l16) * 64];
            o[jt] = __builtin_amdgcn_mfma_f32_16x16x32_bf16(ld8(vr + p0), pf0, o[jt], 0, 0, 0);
            o[jt] = __builtin_amdgcn_mfma_f32_16x16x32_bf16(ld8(vr + p1), pf1, o[jt], 0, 0, 0);
        }
    }

    l += __shfl_xor(l, 16);
    l += __shfl_xor(l, 32);
    float inv = 1.0f / l;
    bf16_t* orow = out + (bS + qw0 + l16) * DIM + h * 64;
    #pragma unroll
    for (int jt = 0; jt < 4; jt++) {
        bf16x4 ov;
        #pragma unroll
        for (int r = 0; r < 4; r++) ov[r] = (bf16_t)(o[jt][r] * inv);
        *(bf16x4*)&orow[jt * 16 + quad * 4] = ov;
    }
}

extern "C" void kernel_launch(void* const* d_in, const int* in_sizes, int n_in,
                              void* d_out, int out_size, void* d_ws, size_t ws_size,
                              hipStream_t stream) {
    const float* x     = (const float*)d_in[0];
    const float* ln1_w = (const float*)d_in[1];
    const float* ln1_b = (const float*)d_in[2];
    const float* w_qkv = (const float*)d_in[3];
    const float* w_o   = (const float*)d_in[4];
    const float* b_o   = (const float*)d_in[5];
    const float* ln2_w = (const float*)d_in[6];
    const float* ln2_b = (const float*)d_in[7];
    const float* w1    = (const float*)d_in[8];
    const float* b1    = (const float*)d_in[9];
    const float* w2    = (const float*)d_in[10];
    const float* b2    = (const float*)d_in[11];
    float* out = (float*)d_out;

    char* ws = (char*)d_ws;
    size_t off = 0;
    auto alloc = [&](size_t bytes) -> char* {
        char* p = ws + off;
        off += (bytes + 255) & ~(size_t)255;
        return p;
    };
    bf16_t* wqkv_t = (bf16_t*)alloc((size_t)DEPTH * DIM * QKVN * 2);
    bf16_t* wo_t   = (bf16_t*)alloc((size_t)DEPTH * DIM * DIM * 2);
    bf16_t* w1_t   = (bf16_t*)alloc((size_t)DEPTH * DIM * MLPD * 2);
    bf16_t* w2_t   = (bf16_t*)alloc((size_t)DEPTH * MLPD * DIM * 2);
    bf16_t* hbuf   = (bf16_t*)alloc((size_t)MTOT * DIM * 2);
    bf16_t* qkvb   = (bf16_t*)alloc((size_t)MTOT * QKVN * 2);   // also Pp slice 0/1
    bf16_t* vtb    = (bf16_t*)alloc((size_t)BATCH * HEADS * 64 * SEQ * 2);
    bf16_t* aob    = (bf16_t*)alloc((size_t)MTOT * DIM * 2);
    bf16_t* midb   = (bf16_t*)alloc((size_t)MTOT * MLPD * 2);
    float*  Pm     = (float*)alloc((size_t)4 * MTOT * DIM * 4); // MLP2 partials
    float*  Pp     = (float*)qkvb;  // proj partials alias dead qkvb+vtb region
    if (off > ws_size) return;

    tcvt_kernel<<<dim3(QKVN / 32, DIM / 32, DEPTH), 256, 0, stream>>>(w_qkv, wqkv_t, DIM, QKVN);
    tcvt_kernel<<<dim3(DIM / 32,  DIM / 32, DEPTH), 256, 0, stream>>>(w_o,   wo_t,   DIM, DIM);
    tcvt_kernel<<<dim3(MLPD / 32, DIM / 32, DEPTH), 256, 0, stream>>>(w1,    w1_t,   DIM, MLPD);
    tcvt_kernel<<<dim3(DIM / 32, MLPD / 32, DEPTH), 256, 0, stream>>>(w2,    w2_t,   MLPD, DIM);

    hipMemcpyAsync(out, x, (size_t)MTOT * DIM * 4, hipMemcpyDeviceToDevice, stream);

    // initial LN1 (layer 0): pure LN of x
    lnr_kernel<<<MTOT / 4, 256, 0, stream>>>(out, nullptr, 0, nullptr,
                                             ln1_w, ln1_b, hbuf, 1);

    for (int L = 0; L < DEPTH; L++) {
        qkv_gemm<<<dim3(QKVN / 64, MTOT / 256, 1), 512, 0, stream>>>(
            hbuf, wqkv_t + (size_t)L * DIM * QKVN, qkvb, vtb);
        attn_kernel<<<dim3(SEQ / 64, HEADS, BATCH), 256, 0, stream>>>(qkvb, vtb, aob);
        // proj: split-2 partial store into Pp (aliases dead qkvb region)
        proj_gemm<<<dim3(DIM / 64, MTOT / 256, 2), 512, 0, stream>>>(
            aob, wo_t + (size_t)L * DIM * DIM, Pp);
        lnr_kernel<<<MTOT / 4, 256, 0, stream>>>(out, Pp, 2, b_o + L * DIM,
                                                 ln2_w + L * DIM, ln2_b + L * DIM,
                                                 hbuf, 1);
        mlp1_gemm<<<dim3(MLPD / 64, MTOT / 256, 1), 512, 0, stream>>>(
            hbuf, w1_t + (size_t)L * DIM * MLPD, b1 + L * MLPD, midb);
        // MLP2: split-4 partial store into Pm
        mlp2_gemm<<<dim3(DIM / 64, MTOT / 256, 4), 512, 0, stream>>>(
            midb, w2_t + (size_t)L * MLPD * DIM, Pm);
        if (L < DEPTH - 1) {
            lnr_kernel<<<MTOT / 4, 256, 0, stream>>>(out, Pm, 4, b2 + L * DIM,
                                                     ln1_w + (L + 1) * DIM,
                                                     ln1_b + (L + 1) * DIM, hbuf, 1);
        } else {
            lnr_kernel<<<MTOT / 4, 256, 0, stream>>>(out, Pm, 4, b2 + L * DIM,
                                                     nullptr, nullptr, nullptr, 0);
        }
    }
}

// Round 12
// 1255.684 us; speedup vs baseline: 1.2435x; 1.0281x over previous
//
#include <hip/hip_runtime.h>
#include <cmath>
#include <cstdint>

typedef __bf16 bf16_t;
typedef __bf16 bf16x8 __attribute__((ext_vector_type(8)));
typedef __bf16 bf16x4 __attribute__((ext_vector_type(4)));
typedef float  f32x4  __attribute__((ext_vector_type(4)));

#define DEPTH 6
#define DIM   768
#define HEADS 12
#define DH    64
#define MLPD  3072
#define SEQ   1024
#define BATCH 4
#define MTOT  (BATCH*SEQ)   /* 4096 rows */
#define QKVN  2304          /* 3*768 */

static __device__ __forceinline__ bf16x8 ld8(const bf16_t* p) {
    return *(const bf16x8*)p;
}

// async global->LDS, 16B per lane. LDS dest is wave-uniform base + lane*16.
// We permute *source* addresses per lane to build XOR-swizzled LDS layouts.
typedef const __attribute__((address_space(1))) unsigned int gas_u32;
typedef __attribute__((address_space(3))) unsigned int las_u32;
static __device__ __forceinline__ void gload16(const bf16_t* g, bf16_t* l) {
    __builtin_amdgcn_global_load_lds((gas_u32*)g, (las_u32*)l, 16, 0, 0);
}

// ---------------- fp32 [K][N] -> bf16 [N][K] transposed weight ----------------
__global__ __launch_bounds__(256) void tcvt_kernel(const float* __restrict__ in,
                                                   bf16_t* __restrict__ out,
                                                   int K, int N) {
    __shared__ float ts[32][33];
    int n0 = blockIdx.x * 32, k0 = blockIdx.y * 32;
    size_t base = (size_t)blockIdx.z * K * N;
    int tx = threadIdx.x & 31, ty = threadIdx.x >> 5;   // 32 x 8
    #pragma unroll
    for (int r = 0; r < 32; r += 8)
        ts[ty + r][tx] = in[base + (size_t)(k0 + ty + r) * N + n0 + tx];
    __syncthreads();
    #pragma unroll
    for (int r = 0; r < 32; r += 8)
        out[base + (size_t)(n0 + ty + r) * K + k0 + tx] = (bf16_t)ts[tx][ty + r];
}

// ------- fused: x += bias + sum(P slices); write x and LN(x) -----------------
// One row per WAVE (256 thr = 4 rows): shuffle-xor butterfly, no LDS/barriers.
__global__ __launch_bounds__(256) void lnr_kernel(float* __restrict__ x,
                                                  const float* __restrict__ P,
                                                  int nslices,
                                                  const float* __restrict__ bias,
                                                  const float* __restrict__ w,
                                                  const float* __restrict__ b,
                                                  bf16_t* __restrict__ h,
                                                  int writeLN) {
    int lane = threadIdx.x & 63;
    int row = blockIdx.x * 4 + (threadIdx.x >> 6);
    float4* xr = (float4*)(x + (size_t)row * DIM);
    float4 v0 = xr[lane], v1 = xr[lane + 64], v2 = xr[lane + 128];
    if (nslices) {
        const float4* bi = (const float4*)bias;
        float4 c0 = bi[lane], c1 = bi[lane + 64], c2 = bi[lane + 128];
        v0.x += c0.x; v0.y += c0.y; v0.z += c0.z; v0.w += c0.w;
        v1.x += c1.x; v1.y += c1.y; v1.z += c1.z; v1.w += c1.w;
        v2.x += c2.x; v2.y += c2.y; v2.z += c2.z; v2.w += c2.w;
        for (int s = 0; s < nslices; s++) {
            const float4* pr = (const float4*)(P + (size_t)s * MTOT * DIM
                                                 + (size_t)row * DIM);
            float4 p0 = pr[lane], p1 = pr[lane + 64], p2 = pr[lane + 128];
            v0.x += p0.x; v0.y += p0.y; v0.z += p0.z; v0.w += p0.w;
            v1.x += p1.x; v1.y += p1.y; v1.z += p1.z; v1.w += p1.w;
            v2.x += p2.x; v2.y += p2.y; v2.z += p2.z; v2.w += p2.w;
        }
        xr[lane] = v0; xr[lane + 64] = v1; xr[lane + 128] = v2;
    }
    float s = v0.x + v0.y + v0.z + v0.w + v1.x + v1.y + v1.z + v1.w
            + v2.x + v2.y + v2.z + v2.w;
    float q = v0.x * v0.x + v0.y * v0.y + v0.z * v0.z + v0.w * v0.w
            + v1.x * v1.x + v1.y * v1.y + v1.z * v1.z + v1.w * v1.w
            + v2.x * v2.x + v2.y * v2.y + v2.z * v2.z + v2.w * v2.w;
    #pragma unroll
    for (int off = 32; off > 0; off >>= 1) {
        s += __shfl_xor(s, off);
        q += __shfl_xor(q, off);
    }
    float mean = s * (1.0f / DIM);
    float rstd = rsqrtf(q * (1.0f / DIM) - mean * mean + 1e-5f);
    if (writeLN) {
        const float4* w4 = (const float4*)w;
        const float4* b4 = (const float4*)b;
        bf16_t* hr = h + (size_t)row * DIM;
        float4 vv[3] = {v0, v1, v2};
        #pragma unroll
        for (int k = 0; k < 3; k++) {
            float4 wv = w4[lane + 64 * k], bv = b4[lane + 64 * k];
            bf16x4 o;
            o[0] = (bf16_t)((vv[k].x - mean) * rstd * wv.x + bv.x);
            o[1] = (bf16_t)((vv[k].y - mean) * rstd * wv.y + bv.y);
            o[2] = (bf16_t)((vv[k].z - mean) * rstd * wv.z + bv.z);
            o[3] = (bf16_t)((vv[k].w - mean) * rstd * wv.w + bv.w);
            *(bf16x4*)&hr[(lane + 64 * k) * 4] = o;
        }
    }
}

// ---------------- bf16 MFMA GEMM body: BM=128, BN=64, BK=64 ------------------
// r11 STRUCTURAL change: BK 32->64. Halves the barrier-event count (the
// measured stall: 56% of cycles neither MFMA nor VALU; per-event stall is
// fill-latency-bound and ~constant, so total stall ~ n_events). LDS =
// 2*(128+64)*64*2B = 48KB -> still 3 blocks/CU (24 waves). Per-CU MFMA
// per event unchanged vs r8 (3 blk x 64 MFMA); events per K halved.
// 256 thr / 4 waves (2m x 2n), wave = 64x32 out, 16 MFMA per event.
// LDS rows are 64 bf16 = 128B = 8 chunks; swizzle pos = chunk ^ (row&7)
// (attn's proven scheme). Staged via per-lane source permute: lane ln ->
// row ln>>3, slot ln&7 holds global chunk (ln&7)^(ln>>3).
// XCD swizzle retained (gridDim.y=32, bijective).
// EPI 0: Cb = A@B; V-tiles (n0>=1536) store transposed into Vt  (QKV)
// EPI 1: Cb = gelu(A@B+bias)                                    (MLP1)
// EPI 2: Cf[slice] = A@B  (plain fp32 partial store, split-K)   (proj/MLP2)
template <int EPI>
static __device__ __forceinline__ void gemm_body(const bf16_t* __restrict__ A,
                                                 const bf16_t* __restrict__ Bt,
                                                 const float* __restrict__ bias,
                                                 bf16_t* __restrict__ Cb,
                                                 float* __restrict__ Cf,
                                                 bf16_t* __restrict__ Vt,
                                                 int N, int K, int klen) {
    __shared__ __align__(16) bf16_t As[2][128 * 64];
    __shared__ __align__(16) bf16_t Bs[2][64 * 64];
    int t = threadIdx.x;
    // XCD-locality remap (bijective: gridDim.y=32, 32%8==0)
    int NX = gridDim.x;
    int flat = blockIdx.y * NX + blockIdx.x;
    int jj = flat >> 3;
    int bxs = jj % NX;
    int bys = (flat & 7) + ((jj / NX) << 3);
    int m0 = bys * 128, n0 = bxs * 64;
    int kz = blockIdx.z;
    int kbeg = kz * klen;
    int lane = t & 63, l16 = lane & 15, quad = lane >> 4;
    int wv = t >> 6;                    // 0..3
    int wm = wv >> 1, wn = wv & 1;      // 2 x 2 wave grid; wave = 64x32 out
    f32x4 acc[4][2] = {};

    // staging: wave wv stages A rows wv*32..+31 (4 instrs, 8 rows each) and
    // B rows wv*16..+15 (2 instrs). lane ln -> row ln>>3 in 8-row group,
    // slot ln&7 holds global chunk (ln&7)^(ln>>3)  [= slot ^ (row&7)].
    int ar = lane >> 3;
    int ac = ((lane & 7) ^ ar) * 8;
    const bf16_t* gA = A  + (size_t)(m0 + wv * 32 + ar) * K + ac;
    const bf16_t* gB = Bt + (size_t)(n0 + wv * 16 + ar) * K + ac;
    bf16_t* lA = &As[0][(wv * 32) * 64];
    bf16_t* lB = &Bs[0][(wv * 16) * 64];
    constexpr int bufA = 128 * 64;
    constexpr int bufB = 64 * 64;

    auto stage = [&](int buf, int k0) {
        #pragma unroll
        for (int i = 0; i < 4; i++)
            gload16(gA + (size_t)(i * 8) * K + k0, lA + buf * bufA + i * 8 * 64);
        #pragma unroll
        for (int i = 0; i < 2; i++)
            gload16(gB + (size_t)(i * 8) * K + k0, lB + buf * bufB + i * 8 * 64);
    };

    int nIt = klen >> 6;
    stage(0, kbeg);
    int rk = l16 & 7;   // row&7 for all frag rows this lane reads

    for (int it = 0; it < nIt; it++) {
        __syncthreads();   // drains own DMA -> buf[it&1] ready; other buf free
        if (it + 1 < nIt) stage((it + 1) & 1, kbeg + (it + 1) * 64);
        const bf16_t* as = As[it & 1];
        const bf16_t* bs = Bs[it & 1];
        #pragma unroll
        for (int kk = 0; kk < 2; kk++) {   // two 16x16x32 k-steps per event
            int pos = ((kk * 4 + quad) ^ rk) * 8;   // swizzled chunk
            bf16x8 af[4], bfr[2];
            #pragma unroll
            for (int i = 0; i < 4; i++)
                af[i] = ld8(&as[(wm * 64 + i * 16 + l16) * 64 + pos]);
            #pragma unroll
            for (int j = 0; j < 2; j++)
                bfr[j] = ld8(&bs[(wn * 32 + j * 16 + l16) * 64 + pos]);
            #pragma unroll
            for (int i = 0; i < 4; i++)
                #pragma unroll
                for (int j = 0; j < 2; j++)
                    acc[i][j] = __builtin_amdgcn_mfma_f32_16x16x32_bf16(af[i], bfr[j], acc[i][j], 0, 0, 0);
        }
    }

    if constexpr (EPI == 0) {
        if (n0 >= 1536) {
            // V tile: store transposed into Vt[b][h][d][n], 8B per store.
            // m0 multiple of 128 -> tile never crosses a batch boundary.
            int b = m0 >> 10;
            #pragma unroll
            for (int i = 0; i < 4; i++) {
                int n = (m0 & 1023) + wm * 64 + i * 16 + quad * 4;
                #pragma unroll
                for (int j = 0; j < 2; j++) {
                    int hc = n0 + wn * 32 + j * 16 + l16 - 1536;
                    int hh = hc >> 6, d = hc & 63;
                    bf16x4 ov;
                    #pragma unroll
                    for (int r = 0; r < 4; r++) ov[r] = (bf16_t)acc[i][j][r];
                    *(bf16x4*)&Vt[(((size_t)b * HEADS + hh) * 64 + d) * SEQ + n] = ov;
                }
            }
            return;
        }
    }
    #pragma unroll
    for (int i = 0; i < 4; i++) {
        int grow = m0 + wm * 64 + i * 16 + quad * 4;
        #pragma unroll
        for (int j = 0; j < 2; j++) {
            int gcol = n0 + wn * 32 + j * 16 + l16;
            float bv = 0.0f;
            if constexpr (EPI == 1) bv = bias[gcol];
            #pragma unroll
            for (int r = 0; r < 4; r++) {
                size_t idx = (size_t)(grow + r) * N + gcol;
                float v = acc[i][j][r];
                if constexpr (EPI == 0) {
                    Cb[idx] = (bf16_t)v;
                } else if constexpr (EPI == 1) {
                    v += bv;
                    v = 0.5f * v * (1.0f + erff(v * 0.70710678118654752f));
                    Cb[idx] = (bf16_t)v;
                } else {
                    Cf[(size_t)kz * MTOT * N + idx] = v;   // plain partial store
                }
            }
        }
    }
}

// Named wrappers: per-shape rocprof attribution.
__global__ __launch_bounds__(256) void qkv_gemm(const bf16_t* __restrict__ A,
                                                const bf16_t* __restrict__ Bt,
                                                bf16_t* __restrict__ Cb,
                                                bf16_t* __restrict__ Vt) {
    gemm_body<0>(A, Bt, nullptr, Cb, nullptr, Vt, QKVN, DIM, DIM);
}
__global__ __launch_bounds__(256) void proj_gemm(const bf16_t* __restrict__ A,
                                                 const bf16_t* __restrict__ Bt,
                                                 float* __restrict__ Cf) {
    gemm_body<2>(A, Bt, nullptr, nullptr, Cf, nullptr, DIM, DIM, 384);
}
__global__ __launch_bounds__(256) void mlp1_gemm(const bf16_t* __restrict__ A,
                                                 const bf16_t* __restrict__ Bt,
                                                 const float* __restrict__ bias,
                                                 bf16_t* __restrict__ Cb) {
    gemm_body<1>(A, Bt, bias, Cb, nullptr, nullptr, MLPD, DIM, DIM);
}
__global__ __launch_bounds__(256) void mlp2_gemm(const bf16_t* __restrict__ A,
                                                 const bf16_t* __restrict__ Bt,
                                                 float* __restrict__ Cf) {
    gemm_body<2>(A, Bt, nullptr, nullptr, Cf, nullptr, DIM, MLPD, 768);
}

// ---------------- flash attention v4 (unchanged) -----------------------------
__global__ __launch_bounds__(256) void attn_kernel(const bf16_t* __restrict__ qkv,
                                                   const bf16_t* __restrict__ vt,
                                                   bf16_t* __restrict__ out) {
    int flat = (blockIdx.z * gridDim.y + blockIdx.y) * gridDim.x + blockIdx.x;
    int jj = flat >> 3;
    int qt = jj & 15;                       // gridDim.x == 16
    int bh = (flat & 7) + ((jj >> 4) << 3); // in [0, 48)
    int h = bh % HEADS, b = bh / HEADS;
    int t = threadIdx.x;
    int wv = t >> 6, lane = t & 63, l16 = lane & 15, quad = lane >> 4;
    const float LOG2E = 1.44269504f;
    int qw0 = qt * 64 + wv * 16;

    __shared__ __align__(16) bf16_t Ks[2][64 * 64];
    __shared__ __align__(16) bf16_t Vs[2][64 * 64];
    __shared__ __align__(16) bf16_t Pa[4][16 * 72];
    bf16_t* P = Pa[wv];

    size_t bS = (size_t)b * SEQ;
    const bf16_t* qrow = qkv + (bS + qw0 + l16) * QKVN + h * 64;
    bf16x8 qf0 = ld8(qrow + quad * 8);
    bf16x8 qf1 = ld8(qrow + 32 + quad * 8);

    float m = -3e38f, l = 0.0f;
    f32x4 o[4] = {};

    const bf16_t* kbase = qkv + bS * QKVN + 768 + h * 64;
    const bf16_t* vbase = vt + ((size_t)(b * HEADS + h) * 64) * SEQ;

    int ar = lane >> 3;
    int ac = ((lane & 7) ^ ar) * 8;
    int i0 = wv * 2, i1 = wv * 2 + 1;
    const bf16_t* gK0 = kbase + (size_t)(i0 * 8 + ar) * QKVN + ac;
    const bf16_t* gK1 = kbase + (size_t)(i1 * 8 + ar) * QKVN + ac;
    const bf16_t* gV0 = vbase + (size_t)(i0 * 8 + ar) * SEQ + ac;
    const bf16_t* gV1 = vbase + (size_t)(i1 * 8 + ar) * SEQ + ac;

    auto stage = [&](int buf, int kb) {
        gload16(gK0 + (size_t)kb * QKVN, &Ks[buf][i0 * 8 * 64]);
        gload16(gK1 + (size_t)kb * QKVN, &Ks[buf][i1 * 8 * 64]);
        gload16(gV0 + kb, &Vs[buf][i0 * 8 * 64]);
        gload16(gV1 + kb, &Vs[buf][i1 * 8 * 64]);
    };

    stage(0, 0);
    int p0 = (quad ^ (l16 & 7)) * 8;         // chunks 0..3 (swizzled)
    int p1 = ((quad + 4) ^ (l16 & 7)) * 8;   // chunks 4..7 (swizzled)

    for (int it = 0; it < SEQ / 64; it++) {
        __syncthreads();
        if (it + 1 < SEQ / 64) stage((it + 1) & 1, (it + 1) * 64);
        const bf16_t* ks = Ks[it & 1];
        const bf16_t* vs = Vs[it & 1];

        f32x4 s[4];
        #pragma unroll
        for (int tt = 0; tt < 4; tt++) {
            const bf16_t* kr = &ks[(tt * 16 + l16) * 64];
            f32x4 z = {};
            z = __builtin_amdgcn_mfma_f32_16x16x32_bf16(ld8(kr + p0), qf0, z, 0, 0, 0);
            z = __builtin_amdgcn_mfma_f32_16x16x32_bf16(ld8(kr + p1), qf1, z, 0, 0, 0);
            s[tt] = z;
        }
        float mx = -3e38f;
        #pragma unroll
        for (int tt = 0; tt < 4; tt++)
            #pragma unroll
            for (int r = 0; r < 4; r++) {
                s[tt][r] *= 0.125f;
                mx = fmaxf(mx, s[tt][r]);
            }
        mx = fmaxf(mx, __shfl_xor(mx, 16));
        mx = fmaxf(mx, __shfl_xor(mx, 32));
        float mn = fmaxf(m, mx);
        float alpha = exp2f((m - mn) * LOG2E);
        m = mn;
        float nb = mn * LOG2E;
        float rs = 0.0f;
        #pragma unroll
        for (int tt = 0; tt < 4; tt++) {
            bf16x4 pkt;
            #pragma unroll
            for (int r = 0; r < 4; r++) {
                float p = exp2f(fmaf(s[tt][r], LOG2E, -nb));
                rs += p;
                pkt[r] = (bf16_t)p;
            }
            *(bf16x4*)&P[l16 * 72 + tt * 16 + quad * 4] = pkt;
        }
        l = l * alpha + rs;   // quad-partial; reduced at end
        #pragma unroll
        for (int jt = 0; jt < 4; jt++) o[jt] *= alpha;
        asm volatile("s_waitcnt lgkmcnt(0)" ::: "memory");  // per-wave P visible
        bf16x8 pf0 = ld8(&P[l16 * 72 + quad * 8]);
        bf16x8 pf1 = ld8(&P[l16 * 72 + 32 + quad * 8]);
        #pragma unroll
        for (int jt = 0; jt < 4; jt++) {
            const bf16_t* vr = &vs[(jt * 16 + l16) * 64];
            o[jt] = __builtin_amdgcn_mfma_f32_16x16x32_bf16(ld8(vr + p0), pf0, o[jt], 0, 0, 0);
            o[jt] = __builtin_amdgcn_mfma_f32_16x16x32_bf16(ld8(vr + p1), pf1, o[jt], 0, 0, 0);
        }
    }

    l += __shfl_xor(l, 16);
    l += __shfl_xor(l, 32);
    float inv = 1.0f / l;
    bf16_t* orow = out + (bS + qw0 + l16) * DIM + h * 64;
    #pragma unroll
    for (int jt = 0; jt < 4; jt++) {
        bf16x4 ov;
        #pragma unroll
        for (int r = 0; r < 4; r++) ov[r] = (bf16_t)(o[jt][r] * inv);
        *(bf16x4*)&orow[jt * 16 + quad * 4] = ov;
    }
}

extern "C" void kernel_launch(void* const* d_in, const int* in_sizes, int n_in,
                              void* d_out, int out_size, void* d_ws, size_t ws_size,
                              hipStream_t stream) {
    const float* x     = (const float*)d_in[0];
    const float* ln1_w = (const float*)d_in[1];
    const float* ln1_b = (const float*)d_in[2];
    const float* w_qkv = (const float*)d_in[3];
    const float* w_o   = (const float*)d_in[4];
    const float* b_o   = (const float*)d_in[5];
    const float* ln2_w = (const float*)d_in[6];
    const float* ln2_b = (const float*)d_in[7];
    const float* w1    = (const float*)d_in[8];
    const float* b1    = (const float*)d_in[9];
    const float* w2    = (const float*)d_in[10];
    const float* b2    = (const float*)d_in[11];
    float* out = (float*)d_out;

    char* ws = (char*)d_ws;
    size_t off = 0;
    auto alloc = [&](size_t bytes) -> char* {
        char* p = ws + off;
        off += (bytes + 255) & ~(size_t)255;
        return p;
    };
    bf16_t* wqkv_t = (bf16_t*)alloc((size_t)DEPTH * DIM * QKVN * 2);
    bf16_t* wo_t   = (bf16_t*)alloc((size_t)DEPTH * DIM * DIM * 2);
    bf16_t* w1_t   = (bf16_t*)alloc((size_t)DEPTH * DIM * MLPD * 2);
    bf16_t* w2_t   = (bf16_t*)alloc((size_t)DEPTH * MLPD * DIM * 2);
    bf16_t* hbuf   = (bf16_t*)alloc((size_t)MTOT * DIM * 2);
    bf16_t* qkvb   = (bf16_t*)alloc((size_t)MTOT * QKVN * 2);   // also Pp slice 0/1
    bf16_t* vtb    = (bf16_t*)alloc((size_t)BATCH * HEADS * 64 * SEQ * 2);
    bf16_t* aob    = (bf16_t*)alloc((size_t)MTOT * DIM * 2);
    bf16_t* midb   = (bf16_t*)alloc((size_t)MTOT * MLPD * 2);
    float*  Pm     = (float*)alloc((size_t)4 * MTOT * DIM * 4); // MLP2 partials
    float*  Pp     = (float*)qkvb;  // proj partials alias dead qkvb+vtb region
    if (off > ws_size) return;

    tcvt_kernel<<<dim3(QKVN / 32, DIM / 32, DEPTH), 256, 0, stream>>>(w_qkv, wqkv_t, DIM, QKVN);
    tcvt_kernel<<<dim3(DIM / 32,  DIM / 32, DEPTH), 256, 0, stream>>>(w_o,   wo_t,   DIM, DIM);
    tcvt_kernel<<<dim3(MLPD / 32, DIM / 32, DEPTH), 256, 0, stream>>>(w1,    w1_t,   DIM, MLPD);
    tcvt_kernel<<<dim3(DIM / 32, MLPD / 32, DEPTH), 256, 0, stream>>>(w2,    w2_t,   MLPD, DIM);

    hipMemcpyAsync(out, x, (size_t)MTOT * DIM * 4, hipMemcpyDeviceToDevice, stream);

    // initial LN1 (layer 0): pure LN of x
    lnr_kernel<<<MTOT / 4, 256, 0, stream>>>(out, nullptr, 0, nullptr,
                                             ln1_w, ln1_b, hbuf, 1);

    for (int L = 0; L < DEPTH; L++) {
        // QKV: 36x32 = 1152 blocks, BK=64 (12 events)
        qkv_gemm<<<dim3(QKVN / 64, MTOT / 128, 1), 256, 0, stream>>>(
            hbuf, wqkv_t + (size_t)L * DIM * QKVN, qkvb, vtb);
        attn_kernel<<<dim3(SEQ / 64, HEADS, BATCH), 256, 0, stream>>>(qkvb, vtb, aob);
        // proj: split-2, 12x32x2 = 768 blocks (6 events each)
        proj_gemm<<<dim3(DIM / 64, MTOT / 128, 2), 256, 0, stream>>>(
            aob, wo_t + (size_t)L * DIM * DIM, Pp);
        lnr_kernel<<<MTOT / 4, 256, 0, stream>>>(out, Pp, 2, b_o + L * DIM,
                                                 ln2_w + L * DIM, ln2_b + L * DIM,
                                                 hbuf, 1);
        // MLP1: 48x32 = 1536 blocks (12 events)
        mlp1_gemm<<<dim3(MLPD / 64, MTOT / 128, 1), 256, 0, stream>>>(
            hbuf, w1_t + (size_t)L * DIM * MLPD, b1 + L * MLPD, midb);
        // MLP2: split-4, 12x32x4 = 1536 blocks (12 events each)
        mlp2_gemm<<<dim3(DIM / 64, MTOT / 128, 4), 256, 0, stream>>>(
            midb, w2_t + (size_t)L * MLPD * DIM, Pm);
        if (L < DEPTH - 1) {
            lnr_kernel<<<MTOT / 4, 256, 0, stream>>>(out, Pm, 4, b2 + L * DIM,
                                                     ln1_w + (L + 1) * DIM,
                                                     ln1_b + (L + 1) * DIM, hbuf, 1);
        } else {
            lnr_kernel<<<MTOT / 4, 256, 0, stream>>>(out, Pm, 4, b2 + L * DIM,
                                                     nullptr, nullptr, nullptr, 0);
        }
    }
}